// Round 1
// baseline (403.005 us; speedup 1.0000x reference)
//
#include <hip/hip_runtime.h>
#include <cstdint>
#include <cstddef>

#define Bn 8
#define Nn 2048
#define Fn 64
#define ALPHA 0.2f

// ---------------- Kernel 1: h = input@W, f1 = h@a1, f2 = h@a2 ----------------
// grid: B*N/4 blocks, 256 threads (4 rows/block, one wave per row)
__global__ __launch_bounds__(256) void k1_h_f(
        const float* __restrict__ inp, const float* __restrict__ W,
        const float* __restrict__ a1, const float* __restrict__ a2,
        float* __restrict__ h, float* __restrict__ f1, float* __restrict__ f2) {
    __shared__ float Wl[Fn * Fn];
    __shared__ float inr[4 * Fn];
    int t = threadIdx.x;
    for (int k = t; k < Fn * Fn; k += 256) Wl[k] = W[k];
    size_t row0 = (size_t)blockIdx.x * 4;
    inr[t] = inp[row0 * Fn + t];   // 4 rows x 64 contiguous floats
    __syncthreads();
    int r = t >> 6, o = t & 63;
    const float* irow = &inr[r * Fn];
    float acc = 0.f;
#pragma unroll
    for (int f = 0; f < Fn; ++f) acc = fmaf(irow[f], Wl[f * Fn + o], acc);
    size_t row = row0 + r;
    h[row * Fn + o] = acc;
    float p = acc * a1[o];
    float q = acc * a2[o];
#pragma unroll
    for (int off = 32; off > 0; off >>= 1) {
        p += __shfl_down(p, off, 64);
        q += __shfl_down(q, off, 64);
    }
    if (o == 0) { f1[row] = p; f2[row] = q; }
}

// ---------------- Kernel 2: column softmax stats + hz partials ----------------
// softmax over axis=1 (i) for each fixed (b,j). Values: adj ? lrelu(f1[i]+f2[j]) : 0.
// grid: (B, N/64), 1024 threads: tx = column-in-chunk (64), ty = i-slice (16).
__global__ __launch_bounds__(1024) void k2_colstats(
        const float* __restrict__ adj, const float* __restrict__ f1,
        const float* __restrict__ f2, const float* __restrict__ h,
        float4* __restrict__ cs, float* __restrict__ hz) {
    int b = blockIdx.x;
    int j0 = blockIdx.y * 64;
    int tx = threadIdx.x & 63, ty = threadIdx.x >> 6;
    int j = j0 + tx;
    float f2j = f2[b * Nn + j];
    float m = -__builtin_inff(), s = 0.f;
    int nz = 0;
    const float* arow = adj + ((size_t)b * Nn) * Nn + j;
    const float* f1b = f1 + b * Nn;
#pragma unroll 4
    for (int i = ty; i < Nn; i += 16) {
        float a = arow[(size_t)i * Nn];
        if (a != 0.f) {
            float x = f1b[i] + f2j;
            float l = x > 0.f ? x : ALPHA * x;
            if (l > m) { s = s * __expf(m - l) + 1.f; m = l; }
            else       { s += __expf(l - m); }
            nz++;
        }
    }
    __shared__ float ms[16][64];
    __shared__ float ss[16][64];
    __shared__ int   nzs[16][64];
    __shared__ float zsh[64];
    ms[ty][tx] = m; ss[ty][tx] = s; nzs[ty][tx] = nz;
    __syncthreads();
    if (ty == 0) {
        float M = m, S = s; int NZ = nz;
        for (int k = 1; k < 16; ++k) {
            float m2 = ms[k][tx], s2 = ss[k][tx];
            NZ += nzs[k][tx];
            if (m2 > M)                    { S = S * __expf(M - m2) + s2; M = m2; }
            else if (m2 > -__builtin_inff()) { S += s2 * __expf(m2 - M); }
        }
        int zeros = Nn - NZ;
        float Mf = (zeros > 0) ? fmaxf(M, 0.f) : M;
        float D = S * __expf(M - Mf) + (float)zeros * __expf(-Mf);
        float R = 1.f / D;
        float z = __expf(-Mf) * R;
        cs[b * Nn + j] = make_float4(f2j, Mf, R, z);
        zsh[tx] = z;
    }
    __syncthreads();
    // hz[b][o] += sum_{j in chunk} z_j * h[b,j,o]   (tx = o, ty = j-slice)
    float part = 0.f;
    for (int jj = ty; jj < 64; jj += 16)
        part = fmaf(zsh[jj], h[((size_t)b * Nn + j0 + jj) * Fn + tx], part);
    ms[ty][tx] = part;
    __syncthreads();
    if (ty == 0) {
        float v = 0.f;
        for (int k = 0; k < 16; ++k) v += ms[k][tx];
        atomicAdd(&hz[b * Fn + tx], v);
    }
}

// ---------------- Kernel 3: sparse aggregation + epilogue ----------------
// h'[b,i,:] = hz[b,:] + sum_{j: adj[b,i,j]!=0} (A[i,j]-z_j) * h[b,j,:]
// out = elu(h' + bias + input).  grid: (B, N/4), 256 threads, one wave per row.
__global__ __launch_bounds__(256) void k3_aggregate(
        const float* __restrict__ adj, const float* __restrict__ f1,
        const float4* __restrict__ cs, const float* __restrict__ h,
        const float* __restrict__ hz, const float* __restrict__ inp,
        const float* __restrict__ bias, float* __restrict__ out) {
    int b = blockIdx.x;
    int ty = threadIdx.x >> 6, lane = threadIdx.x & 63;
    int i = blockIdx.y * 4 + ty;
    float f1i = f1[b * Nn + i];
    const float* arow = adj + (((size_t)b * Nn) + i) * Nn;
    const float4* csb = cs + (size_t)b * Nn;
    const float* hb = h + ((size_t)b * Nn) * Fn;
    float acc = hz[b * Fn + lane];
    for (int j0 = 0; j0 < Nn; j0 += 64) {
        float a = arow[j0 + lane];
        float c = 0.f;
        if (a != 0.f) {
            float4 v = csb[j0 + lane];
            float x = f1i + v.x;
            float l = x > 0.f ? x : ALPHA * x;
            c = __expf(l - v.y) * v.z - v.w;
        }
        unsigned long long mask = __ballot(c != 0.f);
        while (mask) {
            int bit = __builtin_ctzll(mask);
            mask &= mask - 1;
            float coef = __shfl(c, bit, 64);
            acc = fmaf(coef, hb[(size_t)(j0 + bit) * Fn + lane], acc);
        }
    }
    size_t idx = (((size_t)b * Nn) + i) * Fn + lane;
    float hp = acc + bias[i * Fn + lane] + inp[idx];
    out[idx] = hp > 0.f ? hp : __expf(hp) - 1.f;
}

extern "C" void kernel_launch(void* const* d_in, const int* in_sizes, int n_in,
                              void* d_out, int out_size, void* d_ws, size_t ws_size,
                              hipStream_t stream) {
    const float* inp  = (const float*)d_in[0];
    const float* adj  = (const float*)d_in[1];
    const float* W    = (const float*)d_in[2];
    const float* a1   = (const float*)d_in[3];
    const float* a2   = (const float*)d_in[4];
    const float* bias = (const float*)d_in[5];
    float* out = (float*)d_out;

    float* h  = (float*)d_ws;                       // B*N*64 = 1,048,576 floats
    float* f1 = h + (size_t)Bn * Nn * Fn;           // B*N
    float* f2 = f1 + (size_t)Bn * Nn;               // B*N
    float4* cs = (float4*)(f2 + (size_t)Bn * Nn);   // B*N float4 (16B-aligned offset)
    float* hz = (float*)(cs + (size_t)Bn * Nn);     // B*64

    hipMemsetAsync(hz, 0, (size_t)Bn * Fn * sizeof(float), stream);
    k1_h_f<<<Bn * Nn / 4, 256, 0, stream>>>(inp, W, a1, a2, h, f1, f2);
    k2_colstats<<<dim3(Bn, Nn / 64), 1024, 0, stream>>>(adj, f1, f2, h, cs, hz);
    k3_aggregate<<<dim3(Bn, Nn / 4), 256, 0, stream>>>(adj, f1, cs, h, hz, inp, bias, out);
}